// Round 1
// baseline (1266.335 us; speedup 1.0000x reference)
//
#include <hip/hip_runtime.h>
#include <hip/hip_bf16.h>
#include <math.h>

#define BS 8192
#define HID 256
#define SPB1 16

// ---- workspace layout (float element offsets) ----
#define WT1_OFF 0
#define WT2_OFF 65536
#define WT3_OFF 131072
#define WT0_OFF 196608
#define S_OFF   204800
#define C_OFF   (S_OFF + 4 * BS * HID)
#define G_OFF   (C_OFF + 4 * BS * HID)
#define WBT_OFF (G_OFF + BS * 16)
// WBT region: brick-swizzled W: 3 lay x 2 (hi,lo) x 8 nt x 16 kb x 64 lanes x 8 shorts

typedef __attribute__((ext_vector_type(8))) short bf16x8;
typedef __attribute__((ext_vector_type(16))) float f32x16;
#define MFMA32(A, B, C) __builtin_amdgcn_mfma_f32_32x32x16_bf16(A, B, C, 0, 0, 0)

__device__ __forceinline__ ushort bf16_rne(float x) {
    unsigned u = __float_as_uint(x);
    unsigned r = u + 0x7FFFu + ((u >> 16) & 1u);
    return (ushort)(r >> 16);
}
__device__ __forceinline__ void bsplit(float x, ushort& hi, ushort& lo) {
    hi = bf16_rne(x);
    float hf = __uint_as_float(((unsigned)hi) << 16);
    lo = bf16_rne(x - hf);
}

// packed split via v_cvt_pk_bf16_f32 (gfx950)
__device__ __forceinline__ uint pk2(float a, float b) {
    __hip_bfloat162 h = __float22bfloat162_rn(float2{a, b});
    uint u; __builtin_memcpy(&u, &h, 4); return u;
}
__device__ __forceinline__ void split2(float a, float b, uint& hp, uint& lp) {
    hp = pk2(a, b);
    float ha = __uint_as_float(hp << 16);
    float hb = __uint_as_float(hp & 0xFFFF0000u);
    lp = pk2(a - ha, b - hb);
}
__device__ __forceinline__ void split8v(const float* v, uint4& H, uint4& L) {
    split2(v[0], v[1], H.x, L.x);
    split2(v[2], v[3], H.y, L.y);
    split2(v[4], v[5], H.z, L.z);
    split2(v[6], v[7], H.w, L.w);
}

__device__ __forceinline__ void silu_derivs(float a, float& h, float& sp, float& fpp) {
    float sig = 1.0f / (1.0f + __expf(-a));
    float om  = 1.0f - sig;
    h   = a * sig;
    sp  = sig * (1.0f + a * om);                       // silu'
    fpp = sig * om * (2.0f + a * (1.0f - 2.0f * sig)); // silu''
}

// ---------------- kernel 0: weight transposes + bf16 brick swizzle ----------------
__global__ void k_transpose(const float* __restrict__ W0, const float* __restrict__ W1,
                            const float* __restrict__ W2, const float* __restrict__ W3,
                            float* __restrict__ ws) {
    float* WT1 = ws + WT1_OFF;
    float* WT2 = ws + WT2_OFF;
    float* WT3 = ws + WT3_OFF;
    float* WT0 = ws + WT0_OFF;
    ushort* WBT = (ushort*)(ws + WBT_OFF);
    int o = blockIdx.x;      // 0..255 (output col)
    int t = threadIdx.x;     // 0..255 (input row k)
    int which = blockIdx.y;  // 0..3
    if (which < 3) {
        const float* W = (which == 0) ? W1 : (which == 1) ? W2 : W3;
        float* WT = (which == 0) ? WT1 : (which == 1) ? WT2 : WT3;
        float v = W[t * 256 + o];
        WT[o * 256 + t] = v;
        ushort h, l;
        bsplit(v, h, l);
        const int ntg = o >> 5, ln0 = o & 31;
        const int kb = t >> 4, hfb = (t >> 3) & 1, j = t & 7;
        const int laneidx = ln0 + 32 * hfb;
        WBT[(((which * 2 + 0) * 128) + ntg * 16 + kb) * 512 + laneidx * 8 + j] = h;
        WBT[(((which * 2 + 1) * 128) + ntg * 16 + kb) * 512 + laneidx * 8 + j] = l;
    } else if (t < 32) {
        WT0[o * 32 + t] = W0[t * 256 + o]; // WT0[i][k] = W0[k][i]
    }
}

// ---------------- kernel 1: forward + backward (16 samples/block) ----------------
// SPB1=16 halves W-load count per FMA (stage1 is load-latency bound).
// silu'' routed through C (fwd writes raw fpp; bwd same-thread RMW C=dh*fpp)
// to avoid the 48-reg f2a private array that spilled in R3.
__device__ __forceinline__ void fwd16(int L, int t, int m0,
        const float (*Hin)[SPB1], float (*Hout)[SPB1],
        const float* __restrict__ W, const float* __restrict__ b,
        float* __restrict__ S, float* __restrict__ C)
{
    float acc[SPB1];
    #pragma unroll
    for (int s = 0; s < SPB1; ++s) acc[s] = b[t];
    const float4* H4 = (const float4*)&Hin[0][0];
    #pragma unroll 4
    for (int i = 0; i < 256; ++i) {
        float w = W[i * 256 + t];
        #pragma unroll
        for (int q = 0; q < 4; ++q) {
            float4 h = H4[i * 4 + q];
            acc[q * 4 + 0] += h.x * w; acc[q * 4 + 1] += h.y * w;
            acc[q * 4 + 2] += h.z * w; acc[q * 4 + 3] += h.w * w;
        }
    }
    #pragma unroll
    for (int s = 0; s < SPB1; ++s) {
        float h, sp, fpp;
        silu_derivs(acc[s], h, sp, fpp);
        Hout[t][s] = h;
        S[(L * BS + m0 + s) * HID + t] = sp;
        C[(L * BS + m0 + s) * HID + t] = fpp;   // raw silu''; bwd scales it
    }
}

__device__ __forceinline__ void bwd16(int L, int t, int m0,
        const float (*Din)[SPB1], float (*Dout)[SPB1],
        const float* __restrict__ WT,
        const float* __restrict__ S, float* __restrict__ C)
{
    float acc[SPB1];
    #pragma unroll
    for (int s = 0; s < SPB1; ++s) acc[s] = 0.0f;
    const float4* D4 = (const float4*)&Din[0][0];
    #pragma unroll 4
    for (int o = 0; o < 256; ++o) {
        float w = WT[o * 256 + t];
        #pragma unroll
        for (int q = 0; q < 4; ++q) {
            float4 d = D4[o * 4 + q];
            acc[q * 4 + 0] += d.x * w; acc[q * 4 + 1] += d.y * w;
            acc[q * 4 + 2] += d.z * w; acc[q * 4 + 3] += d.w * w;
        }
    }
    #pragma unroll
    for (int s = 0; s < SPB1; ++s) {
        const int idx = (L * BS + m0 + s) * HID + t;
        float dh = acc[s];
        float fpp = C[idx];          // raw silu'' written by fwd (same thread)
        C[idx] = dh * fpp;
        Dout[t][s] = dh * S[idx];    // delta_a
    }
}

__global__ __launch_bounds__(256) void k_stage1(
    const float* __restrict__ z,
    const float* __restrict__ W0, const float* __restrict__ b0,
    const float* __restrict__ W1, const float* __restrict__ b1,
    const float* __restrict__ W2, const float* __restrict__ b2,
    const float* __restrict__ W3, const float* __restrict__ b3,
    const float* __restrict__ W4,
    const float* __restrict__ WT0, const float* __restrict__ WT1,
    const float* __restrict__ WT2, const float* __restrict__ WT3,
    float* __restrict__ S, float* __restrict__ C, float* __restrict__ G)
{
    __shared__ __align__(16) float Zt[32][SPB1];     // [i][s]
    __shared__ __align__(16) float Ha[256][SPB1];
    __shared__ __align__(16) float Hb[256][SPB1];
    const int t  = threadIdx.x;
    const int m0 = blockIdx.x * SPB1;

    for (int e = t; e < 32 * SPB1; e += 256) {
        int i = e >> 4, s = e & 15;
        Zt[i][s] = z[(m0 + s) * 32 + i];
    }
    __syncthreads();

    // ---- layer 1: a1 = z @ W0 + b0 ----
    {
        float acc[SPB1];
        #pragma unroll
        for (int s = 0; s < SPB1; ++s) acc[s] = b0[t];
        const float4* Z4 = (const float4*)&Zt[0][0];
        #pragma unroll 4
        for (int i = 0; i < 32; ++i) {
            float w = W0[i * 256 + t];
            #pragma unroll
            for (int q = 0; q < 4; ++q) {
                float4 zz = Z4[i * 4 + q];
                acc[q * 4 + 0] += zz.x * w; acc[q * 4 + 1] += zz.y * w;
                acc[q * 4 + 2] += zz.z * w; acc[q * 4 + 3] += zz.w * w;
            }
        }
        #pragma unroll
        for (int s = 0; s < SPB1; ++s) {
            float h, sp, fpp;
            silu_derivs(acc[s], h, sp, fpp);
            Ha[t][s] = h;
            S[(0 * BS + m0 + s) * HID + t] = sp;
            C[(0 * BS + m0 + s) * HID + t] = fpp;
        }
    }
    __syncthreads();
    fwd16(1, t, m0, Ha, Hb, W1, b1, S, C);  // h2 in Hb
    __syncthreads();
    fwd16(2, t, m0, Hb, Ha, W2, b2, S, C);  // h3 in Ha
    __syncthreads();
    // ---- layer 4 + start of backward ----
    {
        float acc[SPB1];
        #pragma unroll
        for (int s = 0; s < SPB1; ++s) acc[s] = b3[t];
        const float4* H4 = (const float4*)&Ha[0][0];
        #pragma unroll 4
        for (int i = 0; i < 256; ++i) {
            float w = W3[i * 256 + t];
            #pragma unroll
            for (int q = 0; q < 4; ++q) {
                float4 h = H4[i * 4 + q];
                acc[q * 4 + 0] += h.x * w; acc[q * 4 + 1] += h.y * w;
                acc[q * 4 + 2] += h.z * w; acc[q * 4 + 3] += h.w * w;
            }
        }
        float w4 = W4[t];
        #pragma unroll
        for (int s = 0; s < SPB1; ++s) {
            float h, sp, fpp;
            silu_derivs(acc[s], h, sp, fpp);
            Hb[t][s] = w4 * sp;                          // delta_a4
            C[(3 * BS + m0 + s) * HID + t] = w4 * fpp;   // c4 (final)
        }
    }
    __syncthreads();
    bwd16(2, t, m0, Hb, Ha, WT3, S, C);  // delta_a3 in Ha
    __syncthreads();
    bwd16(1, t, m0, Ha, Hb, WT2, S, C);  // delta_a2 in Hb
    __syncthreads();
    bwd16(0, t, m0, Hb, Ha, WT1, S, C);  // delta_a1 in Ha
    __syncthreads();
    // ---- gradient: g[k] = sum_i W0[k][i] * delta_a1[i] ----
    {
        const int k = t & 31;
        #pragma unroll
        for (int pass = 0; pass < 2; ++pass) {
            const int sh = (t >> 5) + 8 * pass;
            float acc = 0.0f;
            #pragma unroll 4
            for (int i = 0; i < 256; ++i) acc += WT0[i * 32 + k] * Ha[i][sh];
            if (k < 16) G[(m0 + sh) * 16 + k] = acc;
        }
    }
}

// ---------------- kernel 2: 8-wave 32x32 MFMA, PH=128 (2 phases/layer) ----------
// R16: occupancy counter shows 1 block/CU (8 waves) => per-wave reg budget is
// ~256 at no occupancy cost. Changes vs R15:
//   - B fragments (WBT, global-only dependency) prefetched into regs at phase
//     top, so the ~128 KB/phase L2 stream drains UNDER the epilogue instead of
//     serializing after the barrier.
//   - __launch_bounds__(512,2) lifts the VGPR cap (LDS already pins 1 blk/CU).
//   - Tnxt split into TnA/TnB: dependent MFMA chain 24 -> 12 per phase.
#define RSW 136   // shorts per slot row (272 B, ≡4 dwords mod 32 banks)
#define STW 132   // floats per stg row (≡4 mod 32)

__global__ __launch_bounds__(512, 2) void k_stage2(
    const float* __restrict__ z,
    const float* __restrict__ W0,
    const ushort* __restrict__ WBT,
    const float* __restrict__ S, const float* __restrict__ C, const float* __restrict__ G,
    float* __restrict__ out)
{
    // slots: 0=ASh 1=ASl 2=ACh 3=ACl 4=TPh 5=TPl  (each 32 x RSW shorts)
    __shared__ __align__(16) ushort SMEM[6 * 32 * RSW];   // 52224 B
    __shared__ __align__(16) float stg[32 * STW];         // 16896 B
    __shared__ float HCl[32][16];
    __shared__ float Msys[16][17];
    __shared__ float vvs[16];

    const int t    = threadIdx.x;   // 0..511
    const int m    = blockIdx.x;
    const int lane = t & 63;
    const int w    = t >> 6;        // wave 0..7
    const int ln   = lane & 31;
    const int hf   = lane >> 5;
    const int er   = t >> 4;        // epilogue row 0..31
    const int ej   = (t & 15) * 8;  // epilogue col offset 0,8,..120

#define SLOT(a) (&SMEM[(a) * 32 * RSW])

    f32x16 Tacc;   // this wave's T columns (32w + ln), MFMA C-layout
    f32x16 TnA, TnB;   // split accumulators for next-layer T (chain-break)
    f32x16 Dacc;
    #pragma unroll
    for (int r = 0; r < 16; ++r) { Tacc[r] = 0.0f; TnA[r] = 0.0f; TnB[r] = 0.0f; Dacc[r] = 0.0f; }

    // prefetch C/S for (lay=0, p=0)
    float4 cc0, cc1, ss0, ss1;
    {
        const float* Cp = &C[(0 * BS + m) * HID + ej];
        const float* Sp = &S[(0 * BS + m) * HID + ej];
        cc0 = *(const float4*)Cp; cc1 = *(const float4*)(Cp + 4);
        ss0 = *(const float4*)Sp; ss1 = *(const float4*)(Sp + 4);
    }

    for (int lay = 0; lay < 4; ++lay) {
        for (int p = 0; p < 2; ++p) {
            // ---- prefetch this phase's B fragments (global WBT only — no LDS
            //      dependency, so these overlap the whole epilogue below) ----
            bf16x8 BH[8], BL[8];
            if (lay < 3) {
                #pragma unroll
                for (int ks = 0; ks < 8; ++ks) {
                    const int kb = p * 8 + ks;
                    BH[ks] = *(const bf16x8*)&WBT[
                        (((lay * 2 + 0) * 128) + w * 16 + kb) * 512 + lane * 8];
                    BL[ks] = *(const bf16x8*)&WBT[
                        (((lay * 2 + 1) * 128) + w * 16 + kb) * 512 + lane * 8];
                }
            }

            // ---- issue next-phase C/S loads (consumed next phase) ----
            float4 cn0, cn1, sn0, sn1;
            const int nlay = (p < 1) ? lay : lay + 1;
            const int np   = (p < 1) ? 1 : 0;
            if (nlay < 4) {
                const float* Cp = &C[(nlay * BS + m) * HID + np * 128 + ej];
                cn0 = *(const float4*)Cp; cn1 = *(const float4*)(Cp + 4);
                if (nlay < 3) {
                    const float* Sp = &S[(nlay * BS + m) * HID + np * 128 + ej];
                    sn0 = *(const float4*)Sp; sn1 = *(const float4*)(Sp + 4);
                }
            }

            // ---------- epilogue: 512 threads x 8 elements ----------
            {
                float tv[8], tmp[8];
                if (lay == 0) {
                    const float* Wp = &W0[er * HID + p * 128 + ej];
                    *(float4*)&tv[0] = *(const float4*)Wp;
                    *(float4*)&tv[4] = *(const float4*)(Wp + 4);
                } else {
                    *(float4*)&tv[0] = *(const float4*)&stg[er * STW + ej];
                    *(float4*)&tv[4] = *(const float4*)&stg[er * STW + ej + 4];
                }
                uint4 H, L;
                tmp[0] = cc0.x * tv[0]; tmp[1] = cc0.y * tv[1];
                tmp[2] = cc0.z * tv[2]; tmp[3] = cc0.w * tv[3];
                tmp[4] = cc1.x * tv[4]; tmp[5] = cc1.y * tv[5];
                tmp[6] = cc1.z * tv[6]; tmp[7] = cc1.w * tv[7];
                split8v(tmp, H, L);
                *(uint4*)(SLOT(2) + er * RSW + ej) = H;
                *(uint4*)(SLOT(3) + er * RSW + ej) = L;
                if (lay < 3) {
                    tmp[0] = ss0.x * tv[0]; tmp[1] = ss0.y * tv[1];
                    tmp[2] = ss0.z * tv[2]; tmp[3] = ss0.w * tv[3];
                    tmp[4] = ss1.x * tv[4]; tmp[5] = ss1.y * tv[5];
                    tmp[6] = ss1.z * tv[6]; tmp[7] = ss1.w * tv[7];
                    split8v(tmp, H, L);
                    *(uint4*)(SLOT(0) + er * RSW + ej) = H;
                    *(uint4*)(SLOT(1) + er * RSW + ej) = L;
                }
                if (er >= 16) {   // waves 4..7 — wave-uniform branch
                    split8v(tv, H, L);
                    *(uint4*)(SLOT(4) + (er - 16) * RSW + ej) = H;
                    *(uint4*)(SLOT(5) + (er - 16) * RSW + ej) = L;
                }
            }
            __syncthreads();

            // ---------- contraction: ALL 8 waves, wave w takes K-chunk w ----------
            {
                const int ko = w * 16 + hf * 8;
                bf16x8 Bph = *(const bf16x8*)(SLOT(4) + ln * RSW + ko);
                bf16x8 Bpl = *(const bf16x8*)(SLOT(5) + ln * RSW + ko);
                bf16x8 Ah = *(const bf16x8*)(SLOT(2) + ln * RSW + ko);
                bf16x8 Al = *(const bf16x8*)(SLOT(3) + ln * RSW + ko);
                Dacc = MFMA32(Ah, Bph, MFMA32(Al, Bph, MFMA32(Ah, Bpl, Dacc)));
            }

            // ---------- GEMM: all 8 waves, wave w owns n-tile w, 8 K-chunks -------
            // B fragments already in regs; A from LDS; two accumulator chains.
            if (lay < 3) {
                #pragma unroll
                for (int ks = 0; ks < 8; ++ks) {
                    const int ko = ks * 16 + hf * 8;
                    bf16x8 Ah = *(const bf16x8*)(SLOT(0) + ln * RSW + ko);
                    bf16x8 Al = *(const bf16x8*)(SLOT(1) + ln * RSW + ko);
                    TnA = MFMA32(Ah, BH[ks], TnA);
                    TnB = MFMA32(Al, BH[ks], TnB);
                    if (ks & 1) TnA = MFMA32(Ah, BL[ks], TnA);
                    else        TnB = MFMA32(Ah, BL[ks], TnB);
                }
            }

            // ---------- staging dump for the NEXT phase ----------
            if (p == 0) {
                if (lay > 0 && w >= 4) {   // next phase = cols 128..255 (Tacc)
                    #pragma unroll
                    for (int r = 0; r < 16; ++r) {
                        const int row = (r & 3) + 8 * (r >> 2) + 4 * hf;
                        stg[row * STW + (w - 4) * 32 + ln] = Tacc[r];
                    }
                }
            } else {
                if (lay < 3 && w < 4) {    // next layer cols 0..127 (Tnxt)
                    #pragma unroll
                    for (int r = 0; r < 16; ++r) {
                        const int row = (r & 3) + 8 * (r >> 2) + 4 * hf;
                        stg[row * STW + w * 32 + ln] = TnA[r] + TnB[r];
                    }
                }
            }
            __syncthreads();

            // ---- rotate prefetched C/S ----
            if (nlay < 4) {
                cc0 = cn0; cc1 = cn1;
                if (nlay < 3) { ss0 = sn0; ss1 = sn1; }
            }
        } // p

        // ---------- layer end: Tacc <- TnA+TnB (registers only) ----------
        if (lay < 3) {
            #pragma unroll
            for (int r = 0; r < 16; ++r) {
                Tacc[r] = TnA[r] + TnB[r];
                TnA[r] = 0.0f; TnB[r] = 0.0f;
            }
        }
    } // lay

    // ---------- reduce Hessian partials (overlay on SMEM; 16 valid cols) ----
    float* Dred = (float*)SMEM;   // [8][32][16] = 16 KB <= 52 KB
    {
        #pragma unroll
        for (int r = 0; r < 16; ++r) {
            const int row = (r & 3) + 8 * (r >> 2) + 4 * hf;
            if (ln < 16) Dred[(w * 32 + row) * 16 + ln] = Dacc[r];
        }
    }
    __syncthreads();

    // ---------- wave-0 reduce + solve ----------
    if (w == 0) {
        for (int idx = lane; idx < 512; idx += 64) {
            const int row = idx >> 4, j = idx & 15;
            float v = 0.0f;
            #pragma unroll
            for (int wv = 0; wv < 8; ++wv) v += Dred[(wv * 32 + row) * 16 + j];
            HCl[row][j] = v;
        }

        float* M = &Msys[0][0];   // [16][17]
        float vr = 0.0f;
        if (lane < 16) {
            vr = z[m * 32 + 16 + lane];
            vvs[lane] = vr;
        }
        if (lane < 16) {
            #pragma unroll
            for (int j = 0; j < 16; ++j)
                M[lane * 17 + j] = HCl[16 + lane][j] + (lane == j ? 0.2f : 0.0f);
            float r = G[m * 16 + lane];
            #pragma unroll
            for (int j = 0; j < 16; ++j)
                r -= HCl[j][lane] * vvs[j];
            M[lane * 17 + 16] = r;
        }
        // Gauss-Jordan with partial pivoting (wave-synchronous)
        for (int k2 = 0; k2 < 16; ++k2) {
            float val = (lane < 16 && lane >= k2) ? fabsf(M[lane * 17 + k2]) : -1.0f;
            int idx = lane;
            #pragma unroll
            for (int off = 8; off > 0; off >>= 1) {
                float ov = __shfl_xor(val, off, 64);
                int oi = __shfl_xor(idx, off, 64);
                if (ov > val) { val = ov; idx = oi; }
            }
            const int p2 = __shfl(idx, 0, 64);
            if (p2 != k2 && lane < 17) {
                float tmp = M[k2 * 17 + lane];
                M[k2 * 17 + lane] = M[p2 * 17 + lane];
                M[p2 * 17 + lane] = tmp;
            }
            if (lane < 16) {
                const float f = (lane == k2) ? 0.0f : M[lane * 17 + k2] / M[k2 * 17 + k2];
                #pragma unroll
                for (int j = 0; j < 17; ++j)
                    M[lane * 17 + j] -= f * M[k2 * 17 + j];
            }
        }
        if (lane < 16) {
            out[m * 32 + lane]      = vr;
            out[m * 32 + 16 + lane] = M[lane * 17 + 16] / M[lane * 17 + lane];
        }
    }
#undef SLOT
}

extern "C" void kernel_launch(void* const* d_in, const int* in_sizes, int n_in,
                              void* d_out, int out_size, void* d_ws, size_t ws_size,
                              hipStream_t stream) {
    const float* z  = (const float*)d_in[1];
    const float* W0 = (const float*)d_in[2];
    const float* b0 = (const float*)d_in[3];
    const float* W1 = (const float*)d_in[4];
    const float* b1 = (const float*)d_in[5];
    const float* W2 = (const float*)d_in[6];
    const float* b2 = (const float*)d_in[7];
    const float* W3 = (const float*)d_in[8];
    const float* b3 = (const float*)d_in[9];
    const float* W4 = (const float*)d_in[10];
    float* out = (float*)d_out;
    float* ws  = (float*)d_ws;

    float* WT1 = ws + WT1_OFF;
    float* WT2 = ws + WT2_OFF;
    float* WT3 = ws + WT3_OFF;
    float* WT0 = ws + WT0_OFF;
    float* S   = ws + S_OFF;
    float* C   = ws + C_OFF;
    float* G   = ws + G_OFF;
    const ushort* WBT = (const ushort*)(ws + WBT_OFF);

    k_transpose<<<dim3(256, 4), 256, 0, stream>>>(W0, W1, W2, W3, ws);
    k_stage1<<<BS / SPB1, 256, 0, stream>>>(z, W0, b0, W1, b1, W2, b2, W3, b3, W4,
                                            WT0, WT1, WT2, WT3, S, C, G);
    k_stage2<<<BS, 512, 0, stream>>>(z, W0, WBT, S, C, G, out);
}

// Round 2
// 660.288 us; speedup vs baseline: 1.9179x; 1.9179x over previous
//
#include <hip/hip_runtime.h>
#include <hip/hip_bf16.h>
#include <math.h>

#define BS 8192
#define HID 256
#define SPB 32    // samples per block in k_stage1 (MFMA M-tile)

// ---- workspace layout (float element offsets) ----
#define WT1_OFF 0
#define WT2_OFF 65536
#define WT3_OFF 131072
#define WT0_OFF 196608
#define S_OFF   204800
#define C_OFF   (S_OFF + 4 * BS * HID)
#define G_OFF   (C_OFF + 4 * BS * HID)
#define WBT_OFF (G_OFF + BS * 16)
// WBT region: brick-swizzled W: 3 lay x 2 (hi,lo) x 8 nt x 16 kb x 64 lanes x 8 shorts
//   = 393216 shorts = 196608 floats
#define WBTT_OFF (WBT_OFF + 196608)
// WBTT region: same layout for W^T (backward), another 196608 floats

typedef __attribute__((ext_vector_type(8))) short bf16x8;
typedef __attribute__((ext_vector_type(16))) float f32x16;
#define MFMA32(A, B, C) __builtin_amdgcn_mfma_f32_32x32x16_bf16(A, B, C, 0, 0, 0)

__device__ __forceinline__ ushort bf16_rne(float x) {
    unsigned u = __float_as_uint(x);
    unsigned r = u + 0x7FFFu + ((u >> 16) & 1u);
    return (ushort)(r >> 16);
}
__device__ __forceinline__ void bsplit(float x, ushort& hi, ushort& lo) {
    hi = bf16_rne(x);
    float hf = __uint_as_float(((unsigned)hi) << 16);
    lo = bf16_rne(x - hf);
}

// packed split via v_cvt_pk_bf16_f32 (gfx950)
__device__ __forceinline__ uint pk2(float a, float b) {
    __hip_bfloat162 h = __float22bfloat162_rn(float2{a, b});
    uint u; __builtin_memcpy(&u, &h, 4); return u;
}
__device__ __forceinline__ void split2(float a, float b, uint& hp, uint& lp) {
    hp = pk2(a, b);
    float ha = __uint_as_float(hp << 16);
    float hb = __uint_as_float(hp & 0xFFFF0000u);
    lp = pk2(a - ha, b - hb);
}
__device__ __forceinline__ void split8v(const float* v, uint4& H, uint4& L) {
    split2(v[0], v[1], H.x, L.x);
    split2(v[2], v[3], H.y, L.y);
    split2(v[4], v[5], H.z, L.z);
    split2(v[6], v[7], H.w, L.w);
}

__device__ __forceinline__ void silu_derivs(float a, float& h, float& sp, float& fpp) {
    float sig = 1.0f / (1.0f + __expf(-a));
    float om  = 1.0f - sig;
    h   = a * sig;
    sp  = sig * (1.0f + a * om);                       // silu'
    fpp = sig * om * (2.0f + a * (1.0f - 2.0f * sig)); // silu''
}

// ---------------- kernel 0: weight transposes + bf16 brick swizzle ----------------
// Now also emits WBTT = brick-swizzled W^T (for the MFMA backward in stage1).
__global__ void k_transpose(const float* __restrict__ W0, const float* __restrict__ W1,
                            const float* __restrict__ W2, const float* __restrict__ W3,
                            float* __restrict__ ws) {
    float* WT1 = ws + WT1_OFF;
    float* WT2 = ws + WT2_OFF;
    float* WT3 = ws + WT3_OFF;
    float* WT0 = ws + WT0_OFF;
    ushort* WBT  = (ushort*)(ws + WBT_OFF);
    ushort* WBTT = (ushort*)(ws + WBTT_OFF);
    int o = blockIdx.x;      // 0..255 (output col)
    int t = threadIdx.x;     // 0..255 (input row k)
    int which = blockIdx.y;  // 0..3
    if (which < 3) {
        const float* W = (which == 0) ? W1 : (which == 1) ? W2 : W3;
        float* WT = (which == 0) ? WT1 : (which == 1) ? WT2 : WT3;
        float v = W[t * 256 + o];
        WT[o * 256 + t] = v;
        const int ntg = o >> 5, ln0 = o & 31;
        const int kb = t >> 4, hfb = (t >> 3) & 1, j = t & 7;
        const int laneidx = ln0 + 32 * hfb;
        ushort h, l;
        bsplit(v, h, l);
        WBT[(((which * 2 + 0) * 128) + ntg * 16 + kb) * 512 + laneidx * 8 + j] = h;
        WBT[(((which * 2 + 1) * 128) + ntg * 16 + kb) * 512 + laneidx * 8 + j] = l;
        // W^T brick: B[k][n] = W^T[k=t][n=o] = W[o][t]
        float vT = W[o * 256 + t];
        bsplit(vT, h, l);
        WBTT[(((which * 2 + 0) * 128) + ntg * 16 + kb) * 512 + laneidx * 8 + j] = h;
        WBTT[(((which * 2 + 1) * 128) + ntg * 16 + kb) * 512 + laneidx * 8 + j] = l;
    } else if (t < 32) {
        WT0[o * 32 + t] = W0[t * 256 + o]; // WT0[i][k] = W0[k][i]
    }
}

// ---------------- kernel 1: MFMA forward + backward (32 samples/block) ----------
// R17: replaces the fp32-VALU stage1 (15 GFLOP at 157 TF ceiling = 96 us floor,
// achieved ~190 us). All six 256x256 GEMM passes now run on matrix cores with
// the same hi/lo double-bf16 3-term scheme stage2 uses, reusing stage2's WBT
// bricks (forward) and the new WBTT bricks (backward). M=32 samples fills the
// 32x32x16 MFMA M-dim exactly; wave w owns n-tile w (32 cols).
#define RSA 264   // shorts per A-slot row (528 B ≡ 4 dwords mod 32 banks, same
                  // conflict profile as stage2's RSW=136)

__global__ __launch_bounds__(512) void k_stage1(
    const float* __restrict__ z,
    const float* __restrict__ W0, const float* __restrict__ b0,
    const float* __restrict__ b1, const float* __restrict__ b2,
    const float* __restrict__ b3, const float* __restrict__ W4,
    const float* __restrict__ WT0,
    const ushort* __restrict__ WBT, const ushort* __restrict__ WBTT,
    float* __restrict__ S, float* __restrict__ C, float* __restrict__ G)
{
    __shared__ __align__(16) ushort Ah_s[32 * RSA];   // A operand hi [sample][k]
    __shared__ __align__(16) ushort Al_s[32 * RSA];   // A operand lo
    __shared__ __align__(16) float Zt[32][33];        // z tile [sample][dim]

    const int t    = threadIdx.x;     // 0..511
    const int m0   = blockIdx.x * SPB;
    const int lane = t & 63;
    const int w    = t >> 6;          // wave 0..7 = n-tile
    const int ln   = lane & 31;
    const int hf   = lane >> 5;
    const int col  = w * 32 + ln;     // this lane's output column

    for (int e = t; e < 32 * 32; e += 512) {
        int s = e >> 5, i = e & 31;
        Zt[s][i] = z[(m0 + s) * 32 + i];
    }
    __syncthreads();

    // ---- layer 1 (VALU, K=32 is tiny): a1 = z @ W0 + b0 ----
    {
        const int c  = t & 255;
        const int sh = (t >> 8) * 16;     // samples sh..sh+15
        float acc[16];
        const float bb = b0[c];
        #pragma unroll
        for (int s = 0; s < 16; ++s) acc[s] = bb;
        #pragma unroll 4
        for (int i = 0; i < 32; ++i) {
            float w0 = W0[i * 256 + c];
            #pragma unroll
            for (int s = 0; s < 16; ++s) acc[s] += Zt[sh + s][i] * w0;
        }
        #pragma unroll
        for (int s = 0; s < 16; ++s) {
            float h, sp, fpp;
            silu_derivs(acc[s], h, sp, fpp);
            S[(0 * BS + m0 + sh + s) * HID + c] = sp;
            C[(0 * BS + m0 + sh + s) * HID + c] = fpp;
            ushort hh, hl;
            bsplit(h, hh, hl);
            Ah_s[(sh + s) * RSA + c] = hh;
            Al_s[(sh + s) * RSA + c] = hl;
        }
    }

    // ---- forward layers 2..4 (MFMA): a_{L+1} = h_L @ W_L + b_L ----
    for (int lay = 0; lay < 3; ++lay) {
        __syncthreads();   // A-slot writes from previous epilogue visible
        f32x16 acc;
        #pragma unroll
        for (int r = 0; r < 16; ++r) acc[r] = 0.0f;
        #pragma unroll
        for (int ks = 0; ks < 16; ++ks) {
            const int ko = ks * 16 + hf * 8;
            bf16x8 Ahf = *(const bf16x8*)&Ah_s[ln * RSA + ko];
            bf16x8 Alf = *(const bf16x8*)&Al_s[ln * RSA + ko];
            bf16x8 Bh = *(const bf16x8*)&WBT[
                ((lay * 2 + 0) * 128 + w * 16 + ks) * 512 + lane * 8];
            bf16x8 Bl = *(const bf16x8*)&WBT[
                ((lay * 2 + 1) * 128 + w * 16 + ks) * 512 + lane * 8];
            acc = MFMA32(Ahf, Bh, MFMA32(Alf, Bh, MFMA32(Ahf, Bl, acc)));
        }
        __syncthreads();   // all waves done reading A-slots before overwrite
        const float* bptr = (lay == 0) ? b1 : (lay == 1) ? b2 : b3;
        const float bc = bptr[col];
        if (lay < 2) {
            #pragma unroll
            for (int r = 0; r < 16; ++r) {
                const int srow = (r & 3) + 8 * (r >> 2) + 4 * hf;
                float h, sp, fpp;
                silu_derivs(acc[r] + bc, h, sp, fpp);
                S[((lay + 1) * BS + m0 + srow) * HID + col] = sp;
                C[((lay + 1) * BS + m0 + srow) * HID + col] = fpp;
                ushort hh, hl;
                bsplit(h, hh, hl);
                Ah_s[srow * RSA + col] = hh;
                Al_s[srow * RSA + col] = hl;
            }
        } else {           // a4: delta_a4 = W4*silu'(a4); c4 = W4*silu''(a4)
            const float w4v = W4[col];
            #pragma unroll
            for (int r = 0; r < 16; ++r) {
                const int srow = (r & 3) + 8 * (r >> 2) + 4 * hf;
                float h, sp, fpp;
                silu_derivs(acc[r] + bc, h, sp, fpp);
                C[(3 * BS + m0 + srow) * HID + col] = w4v * fpp;
                ushort hh, hl;
                bsplit(w4v * sp, hh, hl);
                Ah_s[srow * RSA + col] = hh;
                Al_s[srow * RSA + col] = hl;
            }
        }
    }

    // ---- backward layers (MFMA with W^T bricks) ----
    for (int blay = 2; blay >= 0; --blay) {
        __syncthreads();
        f32x16 acc;
        #pragma unroll
        for (int r = 0; r < 16; ++r) acc[r] = 0.0f;
        #pragma unroll
        for (int ks = 0; ks < 16; ++ks) {
            const int ko = ks * 16 + hf * 8;
            bf16x8 Ahf = *(const bf16x8*)&Ah_s[ln * RSA + ko];
            bf16x8 Alf = *(const bf16x8*)&Al_s[ln * RSA + ko];
            bf16x8 Bh = *(const bf16x8*)&WBTT[
                ((blay * 2 + 0) * 128 + w * 16 + ks) * 512 + lane * 8];
            bf16x8 Bl = *(const bf16x8*)&WBTT[
                ((blay * 2 + 1) * 128 + w * 16 + ks) * 512 + lane * 8];
            acc = MFMA32(Ahf, Bh, MFMA32(Alf, Bh, MFMA32(Ahf, Bl, acc)));
        }
        __syncthreads();
        #pragma unroll
        for (int r = 0; r < 16; ++r) {
            const int srow = (r & 3) + 8 * (r >> 2) + 4 * hf;
            const int idx = (blay * BS + m0 + srow) * HID + col;
            const float dh  = acc[r];
            const float fpp = C[idx];      // raw silu'' written by forward
            const float sp  = S[idx];
            C[idx] = dh * fpp;
            ushort hh, hl;
            bsplit(dh * sp, hh, hl);       // delta_a
            Ah_s[srow * RSA + col] = hh;
            Al_s[srow * RSA + col] = hl;
        }
    }

    __syncthreads();
    // ---- gradient: g[m][k] = sum_i WT0[i][k] * delta_a1[m][i] ----
    {
        const int s = t >> 4, k = t & 15;
        float accg = 0.0f;
        const ushort* Ap = &Ah_s[s * RSA];
        const ushort* Lp = &Al_s[s * RSA];
        #pragma unroll 4
        for (int i8 = 0; i8 < 32; ++i8) {
            bf16x8 dh8 = *(const bf16x8*)&Ap[i8 * 8];
            bf16x8 dl8 = *(const bf16x8*)&Lp[i8 * 8];
            #pragma unroll
            for (int j = 0; j < 8; ++j) {
                float d = __uint_as_float(((uint)(ushort)dh8[j]) << 16)
                        + __uint_as_float(((uint)(ushort)dl8[j]) << 16);
                accg += WT0[(i8 * 8 + j) * 32 + k] * d;
            }
        }
        G[(m0 + s) * 16 + k] = accg;
    }
}

// ---------------- kernel 2: 8-wave 32x32 MFMA, PH=128 (2 phases/layer) ----------
// FROZEN at the verified-best form (620 us here; R16 post-mortem: 64 VGPR + 48
// AGPR = 112/wave is exactly the 4-wave/SIMD boundary -> TWO blocks/CU
// co-resident; cross-block overlap is what hides the L2 WBT stream. Do not add
// accumulators or live-across-barrier registers to this kernel.)
#define RSW 136   // shorts per slot row (272 B, ≡4 dwords mod 32 banks)
#define STW 132   // floats per stg row (≡4 mod 32)

__global__ __launch_bounds__(512, 4) void k_stage2(
    const float* __restrict__ z,
    const float* __restrict__ W0,
    const ushort* __restrict__ WBT,
    const float* __restrict__ S, const float* __restrict__ C, const float* __restrict__ G,
    float* __restrict__ out)
{
    // slots: 0=ASh 1=ASl 2=ACh 3=ACl 4=TPh 5=TPl  (each 32 x RSW shorts)
    __shared__ __align__(16) ushort SMEM[6 * 32 * RSW];   // 52224 B
    __shared__ __align__(16) float stg[32 * STW];         // 16896 B
    __shared__ float HCl[32][16];
    __shared__ float Msys[16][17];
    __shared__ float vvs[16];

    const int t    = threadIdx.x;   // 0..511
    const int m    = blockIdx.x;
    const int lane = t & 63;
    const int w    = t >> 6;        // wave 0..7
    const int ln   = lane & 31;
    const int hf   = lane >> 5;
    const int er   = t >> 4;        // epilogue row 0..31
    const int ej   = (t & 15) * 8;  // epilogue col offset 0,8,..120

#define SLOT(a) (&SMEM[(a) * 32 * RSW])

    f32x16 Tacc;   // this wave's T columns (32w + ln), MFMA C-layout
    f32x16 Tnxt;
    f32x16 Dacc;
    #pragma unroll
    for (int r = 0; r < 16; ++r) { Tacc[r] = 0.0f; Tnxt[r] = 0.0f; Dacc[r] = 0.0f; }

    // prefetch C/S for (lay=0, p=0)
    float4 cc0, cc1, ss0, ss1;
    {
        const float* Cp = &C[(0 * BS + m) * HID + ej];
        const float* Sp = &S[(0 * BS + m) * HID + ej];
        cc0 = *(const float4*)Cp; cc1 = *(const float4*)(Cp + 4);
        ss0 = *(const float4*)Sp; ss1 = *(const float4*)(Sp + 4);
    }

    for (int lay = 0; lay < 4; ++lay) {
        for (int p = 0; p < 2; ++p) {
            // ---- issue next-phase C/S loads (consumed next phase) ----
            float4 cn0, cn1, sn0, sn1;
            const int nlay = (p < 1) ? lay : lay + 1;
            const int np   = (p < 1) ? 1 : 0;
            if (nlay < 4) {
                const float* Cp = &C[(nlay * BS + m) * HID + np * 128 + ej];
                cn0 = *(const float4*)Cp; cn1 = *(const float4*)(Cp + 4);
                if (nlay < 3) {
                    const float* Sp = &S[(nlay * BS + m) * HID + np * 128 + ej];
                    sn0 = *(const float4*)Sp; sn1 = *(const float4*)(Sp + 4);
                }
            }

            // ---------- epilogue: 512 threads x 8 elements ----------
            {
                float tv[8], tmp[8];
                if (lay == 0) {
                    const float* Wp = &W0[er * HID + p * 128 + ej];
                    *(float4*)&tv[0] = *(const float4*)Wp;
                    *(float4*)&tv[4] = *(const float4*)(Wp + 4);
                } else {
                    *(float4*)&tv[0] = *(const float4*)&stg[er * STW + ej];
                    *(float4*)&tv[4] = *(const float4*)&stg[er * STW + ej + 4];
                }
                uint4 H, L;
                tmp[0] = cc0.x * tv[0]; tmp[1] = cc0.y * tv[1];
                tmp[2] = cc0.z * tv[2]; tmp[3] = cc0.w * tv[3];
                tmp[4] = cc1.x * tv[4]; tmp[5] = cc1.y * tv[5];
                tmp[6] = cc1.z * tv[6]; tmp[7] = cc1.w * tv[7];
                split8v(tmp, H, L);
                *(uint4*)(SLOT(2) + er * RSW + ej) = H;
                *(uint4*)(SLOT(3) + er * RSW + ej) = L;
                if (lay < 3) {
                    tmp[0] = ss0.x * tv[0]; tmp[1] = ss0.y * tv[1];
                    tmp[2] = ss0.z * tv[2]; tmp[3] = ss0.w * tv[3];
                    tmp[4] = ss1.x * tv[4]; tmp[5] = ss1.y * tv[5];
                    tmp[6] = ss1.z * tv[6]; tmp[7] = ss1.w * tv[7];
                    split8v(tmp, H, L);
                    *(uint4*)(SLOT(0) + er * RSW + ej) = H;
                    *(uint4*)(SLOT(1) + er * RSW + ej) = L;
                }
                if (er >= 16) {   // waves 4..7 — wave-uniform branch
                    split8v(tv, H, L);
                    *(uint4*)(SLOT(4) + (er - 16) * RSW + ej) = H;
                    *(uint4*)(SLOT(5) + (er - 16) * RSW + ej) = L;
                }
            }
            __syncthreads();

            // ---------- contraction: ALL 8 waves, wave w takes K-chunk w ----------
            {
                const int ko = w * 16 + hf * 8;
                bf16x8 Bph = *(const bf16x8*)(SLOT(4) + ln * RSW + ko);
                bf16x8 Bpl = *(const bf16x8*)(SLOT(5) + ln * RSW + ko);
                bf16x8 Ah = *(const bf16x8*)(SLOT(2) + ln * RSW + ko);
                bf16x8 Al = *(const bf16x8*)(SLOT(3) + ln * RSW + ko);
                Dacc = MFMA32(Ah, Bph, MFMA32(Al, Bph, MFMA32(Ah, Bpl, Dacc)));
            }

            // ---------- GEMM: all 8 waves, wave w owns n-tile w, 8 K-chunks -------
            if (lay < 3) {
                #pragma unroll
                for (int ks = 0; ks < 8; ++ks) {
                    const int ko = ks * 16 + hf * 8;
                    const int kb = p * 8 + ks;
                    bf16x8 Ah = *(const bf16x8*)(SLOT(0) + ln * RSW + ko);
                    bf16x8 Al = *(const bf16x8*)(SLOT(1) + ln * RSW + ko);
                    bf16x8 Bh = *(const bf16x8*)&WBT[
                        (((lay * 2 + 0) * 128) + w * 16 + kb) * 512 + lane * 8];
                    bf16x8 Bl = *(const bf16x8*)&WBT[
                        (((lay * 2 + 1) * 128) + w * 16 + kb) * 512 + lane * 8];
                    Tnxt = MFMA32(Ah, Bh,
                           MFMA32(Al, Bh,
                           MFMA32(Ah, Bl, Tnxt)));
                }
            }

            // ---------- staging dump for the NEXT phase ----------
            if (p == 0) {
                if (lay > 0 && w >= 4) {   // next phase = cols 128..255 (Tacc)
                    #pragma unroll
                    for (int r = 0; r < 16; ++r) {
                        const int row = (r & 3) + 8 * (r >> 2) + 4 * hf;
                        stg[row * STW + (w - 4) * 32 + ln] = Tacc[r];
                    }
                }
            } else {
                if (lay < 3 && w < 4) {    // next layer cols 0..127 (Tnxt)
                    #pragma unroll
                    for (int r = 0; r < 16; ++r) {
                        const int row = (r & 3) + 8 * (r >> 2) + 4 * hf;
                        stg[row * STW + w * 32 + ln] = Tnxt[r];
                    }
                }
            }
            __syncthreads();

            // ---- rotate prefetched C/S ----
            if (nlay < 4) {
                cc0 = cn0; cc1 = cn1;
                if (nlay < 3) { ss0 = sn0; ss1 = sn1; }
            }
        } // p

        // ---------- layer end: Tacc <- Tnxt (registers only) ----------
        if (lay < 3) {
            Tacc = Tnxt;
            #pragma unroll
            for (int r = 0; r < 16; ++r) Tnxt[r] = 0.0f;
        }
    } // lay

    // ---------- reduce Hessian partials (overlay on SMEM; 16 valid cols) ----
    float* Dred = (float*)SMEM;   // [8][32][16] = 16 KB <= 52 KB
    {
        #pragma unroll
        for (int r = 0; r < 16; ++r) {
            const int row = (r & 3) + 8 * (r >> 2) + 4 * hf;
            if (ln < 16) Dred[(w * 32 + row) * 16 + ln] = Dacc[r];
        }
    }
    __syncthreads();

    // ---------- wave-0 reduce + solve ----------
    if (w == 0) {
        for (int idx = lane; idx < 512; idx += 64) {
            const int row = idx >> 4, j = idx & 15;
            float v = 0.0f;
            #pragma unroll
            for (int wv = 0; wv < 8; ++wv) v += Dred[(wv * 32 + row) * 16 + j];
            HCl[row][j] = v;
        }

        float* M = &Msys[0][0];   // [16][17]
        float vr = 0.0f;
        if (lane < 16) {
            vr = z[m * 32 + 16 + lane];
            vvs[lane] = vr;
        }
        if (lane < 16) {
            #pragma unroll
            for (int j = 0; j < 16; ++j)
                M[lane * 17 + j] = HCl[16 + lane][j] + (lane == j ? 0.2f : 0.0f);
            float r = G[m * 16 + lane];
            #pragma unroll
            for (int j = 0; j < 16; ++j)
                r -= HCl[j][lane] * vvs[j];
            M[lane * 17 + 16] = r;
        }
        // Gauss-Jordan with partial pivoting (wave-synchronous)
        for (int k2 = 0; k2 < 16; ++k2) {
            float val = (lane < 16 && lane >= k2) ? fabsf(M[lane * 17 + k2]) : -1.0f;
            int idx = lane;
            #pragma unroll
            for (int off = 8; off > 0; off >>= 1) {
                float ov = __shfl_xor(val, off, 64);
                int oi = __shfl_xor(idx, off, 64);
                if (ov > val) { val = ov; idx = oi; }
            }
            const int p2 = __shfl(idx, 0, 64);
            if (p2 != k2 && lane < 17) {
                float tmp = M[k2 * 17 + lane];
                M[k2 * 17 + lane] = M[p2 * 17 + lane];
                M[p2 * 17 + lane] = tmp;
            }
            if (lane < 16) {
                const float f = (lane == k2) ? 0.0f : M[lane * 17 + k2] / M[k2 * 17 + k2];
                #pragma unroll
                for (int j = 0; j < 17; ++j)
                    M[lane * 17 + j] -= f * M[k2 * 17 + j];
            }
        }
        if (lane < 16) {
            out[m * 32 + lane]      = vr;
            out[m * 32 + 16 + lane] = M[lane * 17 + 16] / M[lane * 17 + lane];
        }
    }
#undef SLOT
}

extern "C" void kernel_launch(void* const* d_in, const int* in_sizes, int n_in,
                              void* d_out, int out_size, void* d_ws, size_t ws_size,
                              hipStream_t stream) {
    const float* z  = (const float*)d_in[1];
    const float* W0 = (const float*)d_in[2];
    const float* b0 = (const float*)d_in[3];
    const float* W1 = (const float*)d_in[4];
    const float* b1 = (const float*)d_in[5];
    const float* W2 = (const float*)d_in[6];
    const float* b2 = (const float*)d_in[7];
    const float* W3 = (const float*)d_in[8];
    const float* b3 = (const float*)d_in[9];
    const float* W4 = (const float*)d_in[10];
    float* out = (float*)d_out;
    float* ws  = (float*)d_ws;

    float* WT0 = ws + WT0_OFF;
    float* S   = ws + S_OFF;
    float* C   = ws + C_OFF;
    float* G   = ws + G_OFF;
    const ushort* WBT  = (const ushort*)(ws + WBT_OFF);
    const ushort* WBTT = (const ushort*)(ws + WBTT_OFF);

    k_transpose<<<dim3(256, 4), 256, 0, stream>>>(W0, W1, W2, W3, ws);
    k_stage1<<<BS / SPB, 512, 0, stream>>>(z, W0, b0, b1, b2, b3, W4,
                                           WT0, WBT, WBTT, S, C, G);
    k_stage2<<<BS, 512, 0, stream>>>(z, W0, WBT, S, C, G, out);
}